// Round 2
// baseline (1087.355 us; speedup 1.0000x reference)
//
#include <hip/hip_runtime.h>
#include <stdint.h>

#define D_MODEL 5376
#define D_HID   100
#define NH      10
#define WIN     10
#define BATCH   8
#define TLEN    4096
#define M_TOT   (BATCH*TLEN)      // 32768
#define KITERS  (D_MODEL/32)      // 168
#define BM      64

// workspace layout (bytes)
#define WS_W1P  0                 // 168*8192 = 1376256
#define WS_W2P  1376256           // 4*8192   = 32768
#define WS_QVP  1409024           // 4*2048   = 8192
#define WS_B1P  1417216           // 512
#define WS_B2P  1417728           // 512
#define WS_AV   1418240           // 32768*32*4 = 4194304
#define WS_HMAX 5612544           // 80*4

typedef __attribute__((ext_vector_type(8))) short short8;
typedef __attribute__((ext_vector_type(4))) float f32x4;

__device__ __forceinline__ short f2bf(float f) {
    uint32_t u = __float_as_uint(f);
    u += 0x7fff + ((u >> 16) & 1);   // round-to-nearest-even
    return (short)(u >> 16);
}

// ---------------- prep: pack W1/W2/qv to bf16, K-blocked + swizzled ----------
__global__ void prep_kernel(const float* __restrict__ W1, const float* __restrict__ b1,
                            const float* __restrict__ W2, const float* __restrict__ b2,
                            const float* __restrict__ q,  const float* __restrict__ v,
                            char* __restrict__ ws) {
    int id = blockIdx.x * 256 + threadIdx.x;
    if (id < 86016) {                 // W1p: 168 kb * 128 n * 4 kkb
        int kb = id >> 9;
        int rem = id & 511;
        int n = rem >> 2, kkb = rem & 3;
        short8 o;
        #pragma unroll
        for (int j = 0; j < 8; j++) {
            int k = kb * 32 + kkb * 8 + j;
            float val = (n < D_HID) ? W1[n * D_MODEL + k] : 0.f;
            o[j] = f2bf(val);
        }
        int off = kb * 8192 + n * 64 + ((kkb ^ ((n >> 1) & 3)) * 16);
        *(short8*)(ws + WS_W1P + off) = o;
    } else if (id < 86016 + 2048) {   // W2p: 4 kb * 128 n * 4 kkb
        int id2 = id - 86016;
        int kb = id2 >> 9;
        int rem = id2 & 511;
        int n = rem >> 2, kkb = rem & 3;
        short8 o;
        #pragma unroll
        for (int j = 0; j < 8; j++) {
            int k = kb * 32 + kkb * 8 + j;
            float val = (n < D_HID && k < D_HID) ? W2[n * D_HID + k] : 0.f;
            o[j] = f2bf(val);
        }
        int off = kb * 8192 + n * 64 + ((kkb ^ ((n >> 1) & 3)) * 16);
        *(short8*)(ws + WS_W2P + off) = o;
    } else if (id < 86016 + 2048 + 512) {  // qvp: 4 kb * 32 n * 4 kkb
        int id3 = id - 86016 - 2048;
        int kb = id3 >> 7;
        int rem = id3 & 127;
        int n = rem >> 2, kkb = rem & 3;
        short8 o;
        #pragma unroll
        for (int j = 0; j < 8; j++) {
            int k = kb * 32 + kkb * 8 + j;
            float val = 0.f;
            if (k < D_HID) {
                if (n < NH)            val = q[n * D_HID + k];
                else if (n < 2 * NH)   val = v[(n - NH) * D_HID + k];
            }
            o[j] = f2bf(val);
        }
        int off = kb * 2048 + n * 64 + ((kkb ^ ((n >> 1) & 3)) * 16);
        *(short8*)(ws + WS_QVP + off) = o;
    } else {                               // biases, padded to 128
        int id4 = id - 86016 - 2048 - 512;
        if (id4 < 128) {
            ((float*)(ws + WS_B1P))[id4] = (id4 < D_HID) ? b1[id4] : 0.f;
        } else if (id4 < 256) {
            int i = id4 - 128;
            ((float*)(ws + WS_B2P))[i] = (i < D_HID) ? b2[i] : 0.f;
        }
    }
}

// ---------------- fused MLP: x -> h1 -> y -> attn/vals ----------------------
// Restructured: no LDS staging of W1 (B-fragments come straight from global;
// W1p is 1.375 MB and every wave reads identical addresses -> L1/L2 broadcast),
// zero __syncthreads (y1/y2 rows are wave-private), x prefetched 2 iterations
// deep in registers so HBM stays saturated with counted (never-0) vmcnt waits.
__global__ __launch_bounds__(256, 2) void mlp_kernel(
    const float* __restrict__ x, const char* __restrict__ W1p,
    const char* __restrict__ W2p, const char* __restrict__ qvp,
    const float* __restrict__ b1p, const float* __restrict__ b2p,
    float* __restrict__ av) {
    // LDS: y1 (64 x 136 bf16) + y2 — wave-private row slices, no barriers.
    __shared__ __align__(16) char smem[34816];
    short* y1 = (short*)smem;
    short* y2 = (short*)(smem + 17408);

    const int tid = threadIdx.x;
    const int w = tid >> 6, lane = tid & 63;
    const int lr = lane & 15, lq = lane >> 4;
    const int blk = blockIdx.x;
    const int rowbase = blk * BM + w * 16;
    const int swz = (lq ^ ((lr >> 1) & 3)) * 16;

    // A source: x row (rowbase+lr), k chunk lq*8
    const float* xbase = x + (size_t)(rowbase + lr) * D_MODEL + lq * 8;
    const float* xA = xbase;
    // B source: fragment address inside packed tile (same for all waves)
    const char* gB = W1p + lr * 64 + swz;

    f32x4 acc[8];
    #pragma unroll
    for (int i = 0; i < 8; i++) acc[i] = (f32x4)0.f;

    // prologue: x 2-deep (iters 0 and 1), B 1-deep (iter 0)
    float4 axL[2], axH[2];
    axL[0] = *(const float4*)(xA);
    axH[0] = *(const float4*)(xA + 4);
    axL[1] = *(const float4*)(xA + 32);
    axH[1] = *(const float4*)(xA + 36);
    xA += 64;                       // now points at iter-2 chunk
    short8 bf[8];
    #pragma unroll
    for (int nt = 0; nt < 8; nt++) bf[nt] = *(const short8*)(gB + nt * 1024);

    #pragma unroll 2
    for (int i = 0; i < KITERS; i++) {
        const int par = i & 1;
        // convert current A chunk (loaded 2 iterations ago)
        short8 afrag;
        afrag[0] = f2bf(axL[par].x); afrag[1] = f2bf(axL[par].y);
        afrag[2] = f2bf(axL[par].z); afrag[3] = f2bf(axL[par].w);
        afrag[4] = f2bf(axH[par].x); afrag[5] = f2bf(axH[par].y);
        afrag[6] = f2bf(axH[par].z); afrag[7] = f2bf(axH[par].w);
        // prefetch x for iter i+2 into the same parity slot
        // (clamped to a valid address on the last two iterations)
        const float4* px = (const float4*)((i + 2 < KITERS) ? xA : xbase);
        axL[par] = px[0];
        axH[par] = px[1];
        xA += 32;
        // advance B to tile i+1; reload each fragment right after its MFMA
        gB += 8192;                 // last iter reads into W2p region: unused
        #pragma unroll
        for (int nt = 0; nt < 8; nt++) {
            acc[nt] = __builtin_amdgcn_mfma_f32_16x16x32_bf16(afrag, bf[nt], acc[nt], 0, 0, 0);
            bf[nt] = *(const short8*)(gB + nt * 1024);
        }
    }

    // epilogue 1: bias + relu -> y1 (bf16, stride 136); rows are wave-private
    #pragma unroll
    for (int nt = 0; nt < 8; nt++) {
        float bias = b1p[nt * 16 + lr];
        #pragma unroll
        for (int r = 0; r < 4; r++) {
            float vv = acc[nt][r] + bias;
            vv = vv > 0.f ? vv : 0.f;
            y1[(w * 16 + lq * 4 + r) * 136 + nt * 16 + lr] = f2bf(vv);
        }
    }

    // stage 2: h2 = relu(y1 @ W2p^T + b2)   (same-wave rows, no barrier needed)
    f32x4 acc2[8];
    #pragma unroll
    for (int i = 0; i < 8; i++) acc2[i] = (f32x4)0.f;
    #pragma unroll
    for (int kt = 0; kt < 4; kt++) {
        short8 a2 = *(const short8*)(y1 + (w * 16 + lr) * 136 + kt * 32 + lq * 8);
        #pragma unroll
        for (int nt = 0; nt < 8; nt++) {
            short8 b2f = *(const short8*)(W2p + kt * 8192 + (nt * 16 + lr) * 64 + swz);
            acc2[nt] = __builtin_amdgcn_mfma_f32_16x16x32_bf16(a2, b2f, acc2[nt], 0, 0, 0);
        }
    }
    #pragma unroll
    for (int nt = 0; nt < 8; nt++) {
        float bias = b2p[nt * 16 + lr];
        #pragma unroll
        for (int r = 0; r < 4; r++) {
            float vv = acc2[nt][r] + bias;
            vv = vv > 0.f ? vv : 0.f;
            y2[(w * 16 + lq * 4 + r) * 136 + nt * 16 + lr] = f2bf(vv);
        }
    }

    // stage 3: attn/vals = y2 @ qv^T  (cols 0..9 attn, 10..19 vals)
    f32x4 acc3[2];
    acc3[0] = (f32x4)0.f; acc3[1] = (f32x4)0.f;
    #pragma unroll
    for (int kt = 0; kt < 4; kt++) {
        short8 a3 = *(const short8*)(y2 + (w * 16 + lr) * 136 + kt * 32 + lq * 8);
        #pragma unroll
        for (int nt = 0; nt < 2; nt++) {
            short8 b3f = *(const short8*)(qvp + kt * 2048 + (nt * 16 + lr) * 64 + swz);
            acc3[nt] = __builtin_amdgcn_mfma_f32_16x16x32_bf16(a3, b3f, acc3[nt], 0, 0, 0);
        }
    }
    #pragma unroll
    for (int nt = 0; nt < 2; nt++) {
        #pragma unroll
        for (int r = 0; r < 4; r++) {
            av[(size_t)(rowbase + lq * 4 + r) * 32 + nt * 16 + lr] = acc3[nt][r];
        }
    }
}

// ---------------- rolling window softmax pool + max over time ---------------
__global__ void roll_kernel(const float* __restrict__ av, const void* __restrict__ maskp,
                            float* __restrict__ hmax) {
    const int blk = blockIdx.x;
    const int b = blk / NH, h = blk % NH;
    const unsigned char* mb = (const unsigned char*)maskp;
    const int* mi = (const int*)maskp;
    // lengths >= 1024 so mask[0][1] is true: byte layout iff byte[1] != 0
    const bool bytelay = (mb[1] != 0);
    const int tid = threadIdx.x;
    const float* avb = av + (size_t)b * TLEN * 32;
    float lmax = -INFINITY;
    for (int t = tid; t < TLEN; t += 256) {
        bool mt = bytelay ? (mb[b * TLEN + t] != 0) : (mi[b * TLEN + t] != 0);
        if (!mt) continue;
        float wa[WIN], wv[WIN];
        float m = -INFINITY;
        #pragma unroll
        for (int j = 0; j < WIN; j++) {
            int s = t - (WIN - 1) + j;
            bool valid = (s >= 0) &&
                         (bytelay ? (mb[b * TLEN + s] != 0) : (mi[b * TLEN + s] != 0));
            if (valid) { wa[j] = avb[s * 32 + h]; wv[j] = avb[s * 32 + 10 + h]; }
            else       { wa[j] = -INFINITY;       wv[j] = 0.f; }
            m = fmaxf(m, wa[j]);
        }
        float den = 0.f, num = 0.f;
        #pragma unroll
        for (int j = 0; j < WIN; j++) {
            float e = __expf(wa[j] - m);   // exp(-inf) = 0 kills invalid slots
            den += e;
            num += e * wv[j];
        }
        lmax = fmaxf(lmax, num / den);
    }
    #pragma unroll
    for (int off = 32; off >= 1; off >>= 1)
        lmax = fmaxf(lmax, __shfl_down(lmax, off));
    __shared__ float red[4];
    if ((tid & 63) == 0) red[tid >> 6] = lmax;
    __syncthreads();
    if (tid == 0) {
        hmax[blk] = fmaxf(fmaxf(red[0], red[1]), fmaxf(red[2], red[3]));
    }
}

// ---------------- final: sum heads + bias -----------------------------------
__global__ void final_kernel(const float* __restrict__ hmax, const float* __restrict__ bias,
                             float* __restrict__ out) {
    int tid = threadIdx.x;
    if (tid < BATCH) {
        float s = bias[0];
        #pragma unroll
        for (int h = 0; h < NH; h++) s += hmax[tid * NH + h];
        out[tid] = s;
    }
}

extern "C" void kernel_launch(void* const* d_in, const int* in_sizes, int n_in,
                              void* d_out, int out_size, void* d_ws, size_t ws_size,
                              hipStream_t stream) {
    const float* x    = (const float*)d_in[0];
    const void*  mask = d_in[1];
    const float* W1   = (const float*)d_in[2];
    const float* b1   = (const float*)d_in[3];
    const float* W2   = (const float*)d_in[4];
    const float* b2   = (const float*)d_in[5];
    const float* q    = (const float*)d_in[6];
    const float* v    = (const float*)d_in[7];
    const float* bias = (const float*)d_in[8];
    char* ws = (char*)d_ws;

    const char*  W1p  = ws + WS_W1P;
    const char*  W2p  = ws + WS_W2P;
    const char*  qvp  = ws + WS_QVP;
    const float* b1p  = (const float*)(ws + WS_B1P);
    const float* b2p  = (const float*)(ws + WS_B2P);
    float*       av   = (float*)(ws + WS_AV);
    float*       hmax = (float*)(ws + WS_HMAX);

    prep_kernel<<<dim3(347), dim3(256), 0, stream>>>(W1, b1, W2, b2, q, v, ws);
    mlp_kernel<<<dim3(M_TOT / BM), dim3(256), 0, stream>>>(x, W1p, W2p, qvp, b1p, b2p, av);
    roll_kernel<<<dim3(BATCH * NH), dim3(256), 0, stream>>>(av, mask, hmax);
    final_kernel<<<dim3(1), dim3(64), 0, stream>>>(hmax, bias, (float*)d_out);
}

// Round 4
// 945.445 us; speedup vs baseline: 1.1501x; 1.1501x over previous
//
#include <hip/hip_runtime.h>
#include <stdint.h>

#define D_MODEL 5376
#define D_HID   100
#define NH      10
#define WIN     10
#define BATCH   8
#define TLEN    4096
#define M_TOT   (BATCH*TLEN)      // 32768
#define KITERS  (D_MODEL/32)      // 168
#define BM      64
#define NCHUNK  16                // roll_kernel T-split

// workspace layout (bytes)
#define WS_W1P  0                 // 168*8192 = 1376256
#define WS_W2P  1376256           // 4*8192   = 32768
#define WS_QVP  1409024           // 4*2048   = 8192
#define WS_B1P  1417216           // 512
#define WS_B2P  1417728           // 512
#define WS_AV   1418240           // 32768*32*4 = 4194304
#define WS_HMAX 5612544           // 80*NCHUNK*4 = 5120

typedef __attribute__((ext_vector_type(8))) short short8;
typedef __attribute__((ext_vector_type(4))) float f32x4;

__device__ __forceinline__ short f2bf(float f) {
    uint32_t u = __float_as_uint(f);
    u += 0x7fff + ((u >> 16) & 1);   // round-to-nearest-even
    return (short)(u >> 16);
}

// async global -> LDS, 16B per lane (m97 pattern). LDS dest must be
// wave-uniform base; HW writes base + lane*16.
__device__ __forceinline__ void gload_lds16(const char* g, char* l) {
    __builtin_amdgcn_global_load_lds(
        (const __attribute__((address_space(1))) void*)g,
        (__attribute__((address_space(3))) void*)l,
        16, 0, 0);
}

// ---------------- prep: pack W1/W2/qv to bf16, K-blocked + swizzled ----------
__global__ void prep_kernel(const float* __restrict__ W1, const float* __restrict__ b1,
                            const float* __restrict__ W2, const float* __restrict__ b2,
                            const float* __restrict__ q,  const float* __restrict__ v,
                            char* __restrict__ ws) {
    int id = blockIdx.x * 256 + threadIdx.x;
    if (id < 86016) {                 // W1p: 168 kb * 128 n * 4 kkb
        int kb = id >> 9;
        int rem = id & 511;
        int n = rem >> 2, kkb = rem & 3;
        short8 o;
        #pragma unroll
        for (int j = 0; j < 8; j++) {
            int k = kb * 32 + kkb * 8 + j;
            float val = (n < D_HID) ? W1[n * D_MODEL + k] : 0.f;
            o[j] = f2bf(val);
        }
        int off = kb * 8192 + n * 64 + ((kkb ^ ((n >> 1) & 3)) * 16);
        *(short8*)(ws + WS_W1P + off) = o;
    } else if (id < 86016 + 2048) {   // W2p: 4 kb * 128 n * 4 kkb
        int id2 = id - 86016;
        int kb = id2 >> 9;
        int rem = id2 & 511;
        int n = rem >> 2, kkb = rem & 3;
        short8 o;
        #pragma unroll
        for (int j = 0; j < 8; j++) {
            int k = kb * 32 + kkb * 8 + j;
            float val = (n < D_HID && k < D_HID) ? W2[n * D_HID + k] : 0.f;
            o[j] = f2bf(val);
        }
        int off = kb * 8192 + n * 64 + ((kkb ^ ((n >> 1) & 3)) * 16);
        *(short8*)(ws + WS_W2P + off) = o;
    } else if (id < 86016 + 2048 + 512) {  // qvp: 4 kb * 32 n * 4 kkb
        int id3 = id - 86016 - 2048;
        int kb = id3 >> 7;
        int rem = id3 & 127;
        int n = rem >> 2, kkb = rem & 3;
        short8 o;
        #pragma unroll
        for (int j = 0; j < 8; j++) {
            int k = kb * 32 + kkb * 8 + j;
            float val = 0.f;
            if (k < D_HID) {
                if (n < NH)            val = q[n * D_HID + k];
                else if (n < 2 * NH)   val = v[(n - NH) * D_HID + k];
            }
            o[j] = f2bf(val);
        }
        int off = kb * 2048 + n * 64 + ((kkb ^ ((n >> 1) & 3)) * 16);
        *(short8*)(ws + WS_QVP + off) = o;
    } else {                               // biases, padded to 128
        int id4 = id - 86016 - 2048 - 512;
        if (id4 < 128) {
            ((float*)(ws + WS_B1P))[id4] = (id4 < D_HID) ? b1[id4] : 0.f;
        } else if (id4 < 256) {
            int i = id4 - 128;
            ((float*)(ws + WS_B2P))[i] = (i < D_HID) ? b2[i] : 0.f;
        }
    }
}

// ---------------- fused MLP: x -> h1 -> y -> attn/vals ----------------------
// Round-0 structure (LDS double-buffered B tiles, barrier per K-step) with the
// B staging done by async global_load_lds width-16 (no VGPR round-trip, no
// ds_write). LDS content is byte-identical to the reg-staged version:
// LDS[b] = W1p[i*8192 + b]. x prefetched 1 iter ahead in regs (as round 0) —
// deeper prefetch is pointless: the per-iteration barrier drains vmcnt(0).
__global__ __launch_bounds__(256, 2) void mlp_kernel(
    const float* __restrict__ x, const char* __restrict__ W1p,
    const char* __restrict__ W2p, const char* __restrict__ qvp,
    const float* __restrict__ b1p, const float* __restrict__ b2p,
    float* __restrict__ av) {
    // LDS: [0,16384) = W1 tile double-buffer during K-loop;
    //      [0,17408) = y1 (64 x 136 bf16), [17408,34816) = y2 (after K-loop)
    __shared__ __align__(16) char smem[34816];
    short* y1 = (short*)smem;
    short* y2 = (short*)(smem + 17408);

    const int tid = threadIdx.x;
    const int w = tid >> 6, lane = tid & 63;
    const int lr = lane & 15, lq = lane >> 4;
    const int blk = blockIdx.x;
    const int rowbase = blk * BM + w * 16;
    const int swz = (lq ^ ((lr >> 1) & 3)) * 16;

    // A-fragment source: x row (rowbase+lr), k chunk lq*8
    const float* xA = x + (size_t)(rowbase + lr) * D_MODEL + lq * 8;
    // B async-staging source: per-lane 16B, wave w covers [w*2048, w*2048+2048)
    const char* gB0 = W1p + w * 2048 + lane * 16;

    f32x4 acc[8];
    #pragma unroll
    for (int i = 0; i < 8; i++) acc[i] = (f32x4)0.f;

    // prologue: async-stage tile 0 into buf0; x regs for iter 0
    gload_lds16(gB0,        smem + w * 2048);
    gload_lds16(gB0 + 1024, smem + w * 2048 + 1024);
    float4 a0 = *(const float4*)(xA);
    float4 a1 = *(const float4*)(xA + 4);
    __syncthreads();                    // vmcnt(0) drain -> buf0 complete

    #pragma unroll 2
    for (int i = 0; i < KITERS; i++) {
        // consume A regs -> bf16 fragment (before the regs are re-loaded)
        short8 afrag;
        afrag[0] = f2bf(a0.x); afrag[1] = f2bf(a0.y);
        afrag[2] = f2bf(a0.z); afrag[3] = f2bf(a0.w);
        afrag[4] = f2bf(a1.x); afrag[5] = f2bf(a1.y);
        afrag[6] = f2bf(a1.z); afrag[7] = f2bf(a1.w);
        // issue next tile (async -> other buffer) + next x chunk
        if (i + 1 < KITERS) {
            const char* gBn = gB0 + (i + 1) * 8192;
            char* lb = smem + ((i + 1) & 1) * 8192 + w * 2048;
            gload_lds16(gBn,        lb);
            gload_lds16(gBn + 1024, lb + 1024);
            xA += 32;
            a0 = *(const float4*)(xA);
            a1 = *(const float4*)(xA + 4);
        }
        // compute from current buffer
        const char* bbr = smem + (i & 1) * 8192;
        const int baddr = lr * 64 + swz;
        #pragma unroll
        for (int nt = 0; nt < 8; nt++) {
            short8 bfrag = *(const short8*)(bbr + baddr + nt * 1024);
            acc[nt] = __builtin_amdgcn_mfma_f32_16x16x32_bf16(afrag, bfrag, acc[nt], 0, 0, 0);
        }
        __syncthreads();                // drains next-tile async loads + x regs
    }

    // epilogue 1: bias + relu -> y1 (bf16, stride 136)
    #pragma unroll
    for (int nt = 0; nt < 8; nt++) {
        float bias = b1p[nt * 16 + lr];
        #pragma unroll
        for (int r = 0; r < 4; r++) {
            float vv = acc[nt][r] + bias;
            vv = vv > 0.f ? vv : 0.f;
            y1[(w * 16 + lq * 4 + r) * 136 + nt * 16 + lr] = f2bf(vv);
        }
    }
    __syncthreads();

    // stage 2: h2 = relu(y1 @ W2p^T + b2)
    f32x4 acc2[8];
    #pragma unroll
    for (int i = 0; i < 8; i++) acc2[i] = (f32x4)0.f;
    #pragma unroll
    for (int kt = 0; kt < 4; kt++) {
        short8 a2 = *(const short8*)(y1 + (w * 16 + lr) * 136 + kt * 32 + lq * 8);
        #pragma unroll
        for (int nt = 0; nt < 8; nt++) {
            short8 b2f = *(const short8*)(W2p + kt * 8192 + (nt * 16 + lr) * 64 + swz);
            acc2[nt] = __builtin_amdgcn_mfma_f32_16x16x32_bf16(a2, b2f, acc2[nt], 0, 0, 0);
        }
    }
    #pragma unroll
    for (int nt = 0; nt < 8; nt++) {
        float bias = b2p[nt * 16 + lr];
        #pragma unroll
        for (int r = 0; r < 4; r++) {
            float vv = acc2[nt][r] + bias;
            vv = vv > 0.f ? vv : 0.f;
            y2[(w * 16 + lq * 4 + r) * 136 + nt * 16 + lr] = f2bf(vv);
        }
    }
    __syncthreads();

    // stage 3: attn/vals = y2 @ qv^T  (cols 0..9 attn, 10..19 vals)
    f32x4 acc3[2];
    acc3[0] = (f32x4)0.f; acc3[1] = (f32x4)0.f;
    #pragma unroll
    for (int kt = 0; kt < 4; kt++) {
        short8 a3 = *(const short8*)(y2 + (w * 16 + lr) * 136 + kt * 32 + lq * 8);
        #pragma unroll
        for (int nt = 0; nt < 2; nt++) {
            short8 b3f = *(const short8*)(qvp + kt * 2048 + (nt * 16 + lr) * 64 + swz);
            acc3[nt] = __builtin_amdgcn_mfma_f32_16x16x32_bf16(a3, b3f, acc3[nt], 0, 0, 0);
        }
    }
    #pragma unroll
    for (int nt = 0; nt < 2; nt++) {
        #pragma unroll
        for (int r = 0; r < 4; r++) {
            av[(size_t)(rowbase + lq * 4 + r) * 32 + nt * 16 + lr] = acc3[nt][r];
        }
    }
}

// ---------------- rolling window softmax pool + partial max over time -------
// T split into NCHUNK chunks -> 80*NCHUNK blocks (good CU coverage; old
// version used 80 blocks = 31% of CUs). Each thread owns exactly one t.
__global__ void roll_kernel(const float* __restrict__ av, const void* __restrict__ maskp,
                            float* __restrict__ hpart) {
    const int blk = blockIdx.x;
    const int c  = blk & (NCHUNK - 1);
    const int bh = blk / NCHUNK;
    const int b = bh / NH, h = bh % NH;
    const unsigned char* mb = (const unsigned char*)maskp;
    const int* mi = (const int*)maskp;
    // lengths >= 1024 so mask[0][1] is true: byte layout iff byte[1] != 0
    const bool bytelay = (mb[1] != 0);
    const int tid = threadIdx.x;
    const float* avb = av + (size_t)b * TLEN * 32;
    const int t = c * (TLEN / NCHUNK) + tid;   // TLEN/NCHUNK == 256 == blockDim
    float lmax = -INFINITY;
    bool mt = bytelay ? (mb[b * TLEN + t] != 0) : (mi[b * TLEN + t] != 0);
    if (mt) {
        float wa[WIN], wv[WIN];
        float m = -INFINITY;
        #pragma unroll
        for (int j = 0; j < WIN; j++) {
            int s = t - (WIN - 1) + j;
            bool valid = (s >= 0) &&
                         (bytelay ? (mb[b * TLEN + s] != 0) : (mi[b * TLEN + s] != 0));
            if (valid) { wa[j] = avb[s * 32 + h]; wv[j] = avb[s * 32 + 10 + h]; }
            else       { wa[j] = -INFINITY;       wv[j] = 0.f; }
            m = fmaxf(m, wa[j]);
        }
        float den = 0.f, num = 0.f;
        #pragma unroll
        for (int j = 0; j < WIN; j++) {
            float e = __expf(wa[j] - m);   // exp(-inf) = 0 kills invalid slots
            den += e;
            num += e * wv[j];
        }
        lmax = num / den;
    }
    #pragma unroll
    for (int off = 32; off >= 1; off >>= 1)
        lmax = fmaxf(lmax, __shfl_down(lmax, off));
    __shared__ float red[4];
    if ((tid & 63) == 0) red[tid >> 6] = lmax;
    __syncthreads();
    if (tid == 0) {
        hpart[bh * NCHUNK + c] = fmaxf(fmaxf(red[0], red[1]), fmaxf(red[2], red[3]));
    }
}

// ---------------- final: reduce chunks, sum heads + bias --------------------
__global__ void final_kernel(const float* __restrict__ hpart, const float* __restrict__ bias,
                             float* __restrict__ out) {
    __shared__ float red[BATCH * NH];
    int tid = threadIdx.x;
    if (tid < BATCH * NH) {
        float m = -INFINITY;
        #pragma unroll
        for (int c = 0; c < NCHUNK; c++) m = fmaxf(m, hpart[tid * NCHUNK + c]);
        red[tid] = m;
    }
    __syncthreads();
    if (tid < BATCH) {
        float s = bias[0];
        #pragma unroll
        for (int h = 0; h < NH; h++) s += red[tid * NH + h];
        out[tid] = s;
    }
}

extern "C" void kernel_launch(void* const* d_in, const int* in_sizes, int n_in,
                              void* d_out, int out_size, void* d_ws, size_t ws_size,
                              hipStream_t stream) {
    const float* x    = (const float*)d_in[0];
    const void*  mask = d_in[1];
    const float* W1   = (const float*)d_in[2];
    const float* b1   = (const float*)d_in[3];
    const float* W2   = (const float*)d_in[4];
    const float* b2   = (const float*)d_in[5];
    const float* q    = (const float*)d_in[6];
    const float* v    = (const float*)d_in[7];
    const float* bias = (const float*)d_in[8];
    char* ws = (char*)d_ws;

    const char*  W1p  = ws + WS_W1P;
    const char*  W2p  = ws + WS_W2P;
    const char*  qvp  = ws + WS_QVP;
    const float* b1p  = (const float*)(ws + WS_B1P);
    const float* b2p  = (const float*)(ws + WS_B2P);
    float*       av   = (float*)(ws + WS_AV);
    float*       hpart= (float*)(ws + WS_HMAX);

    prep_kernel<<<dim3(347), dim3(256), 0, stream>>>(W1, b1, W2, b2, q, v, ws);
    mlp_kernel<<<dim3(M_TOT / BM), dim3(256), 0, stream>>>(x, W1p, W2p, qvp, b1p, b2p, av);
    roll_kernel<<<dim3(BATCH * NH * NCHUNK), dim3(256), 0, stream>>>(av, mask, hpart);
    final_kernel<<<dim3(1), dim3(128), 0, stream>>>(hpart, bias, (float*)d_out);
}